// Round 16
// baseline (209.050 us; speedup 1.0000x reference)
//
#include <hip/hip_runtime.h>
#include <hip/hip_bf16.h>

#define TT 4096
#define CC 1024
#define NHEAD 16
#define DH 64
#define N3C 3072

typedef __attribute__((ext_vector_type(8))) short short8;
typedef __attribute__((ext_vector_type(4))) float floatx4;
typedef __attribute__((ext_vector_type(16))) float floatx16;
typedef __attribute__((ext_vector_type(4))) unsigned int uint4v;

// Q pre-scale: 1/sqrt(64) * log2(e)  (softmax in exp2 domain, m=0 fixed)
#define QSCALE 0.18033688011112042f

__device__ __forceinline__ short f2bf(float f) {
    union { __hip_bfloat16 h; short s; } u;
    u.h = __float2bfloat16(f);
    return u.s;
}

// async global->LDS 16B per lane; LDS dest = wave-uniform base + lane*16
__device__ __forceinline__ void gload_lds16(const void* g, void* l) {
    __builtin_amdgcn_global_load_lds(
        (const __attribute__((address_space(1))) unsigned int*)(unsigned long long)g,
        (__attribute__((address_space(3))) unsigned int*)(unsigned int)(unsigned long long)l,
        16, 0, 0);
}

// pack two fp32 -> bf16x2 by truncation (1 v_perm) — used only for attn P
__device__ __forceinline__ unsigned pk_trunc(float lo, float hi) {
    return __builtin_amdgcn_perm(__float_as_uint(hi), __float_as_uint(lo), 0x07060302u);
}

// pack two fp32 -> bf16x2 with RNE rounding (numerics identical to f2bf path)
__device__ __forceinline__ unsigned pk_rne(float lo, float hi) {
    unsigned a = (unsigned short)f2bf(lo);
    unsigned b = (unsigned short)f2bf(hi);
    return a | (b << 16);
}

// ---------------- fused prep: cvt x->bf16, transpose both weights ----------------
__device__ __forceinline__ void tr_body(const float* __restrict__ in, short* __restrict__ out,
                                        int K, int N, int bx, int by, int tid, float (*tile)[33]) {
    int nt = bx * 32, kt = by * 32;
    int tx = tid & 31, ty = tid >> 5;
#pragma unroll
    for (int i = 0; i < 32; i += 8)
        tile[ty + i][tx] = in[(size_t)(kt + ty + i) * N + nt + tx];
    __syncthreads();
#pragma unroll
    for (int i = 0; i < 32; i += 8)
        out[(size_t)(nt + ty + i) * K + kt + tx] = f2bf(tile[tx][ty + i]);
}

__global__ void k_prep(const float* __restrict__ x, short* __restrict__ xb,
                       const float* __restrict__ w_qkv, short* __restrict__ wqkvT,
                       const float* __restrict__ w_proj, short* __restrict__ wprojT) {
    __shared__ float tile[32][33];
    int id = blockIdx.x;
    int tid = threadIdx.x;
    if (id < 4096) {
        int i = (id * 256 + tid) * 4;
        float4 v = *(const float4*)&x[i];
        short4 r;
        r.x = f2bf(v.x); r.y = f2bf(v.y); r.z = f2bf(v.z); r.w = f2bf(v.w);
        *(short4*)&xb[i] = r;
    } else if (id < 4096 + 3072) {
        int r = id - 4096;
        tr_body(w_qkv, wqkvT, CC, N3C, r % 96, r / 96, tid, tile);
    } else {
        int r = id - 7168;
        tr_body(w_proj, wprojT, CC, CC, r & 31, r >> 5, tid, tile);
    }
}

// ---------------- GEMM1 v2: qkv = x @ w_qkv + b, LDS re-layout epilogue -----------
__global__ __launch_bounds__(256) void k_gemm_qkv(const short* __restrict__ A,
                                                  const short* __restrict__ Bt,
                                                  const float* __restrict__ bias,
                                                  short* __restrict__ Q,
                                                  short* __restrict__ Kb,
                                                  short* __restrict__ Vtg) {
    const int m0 = blockIdx.y * 128;
    const int n0 = blockIdx.x * 128;
    __shared__ __attribute__((aligned(16))) short Sbuf[4][128 * 32];  // As=0/1, Bs=2/3
    const int tid = threadIdx.x;
    const int lane = tid & 63;
    const int w = tid >> 6;
    const int wm = w >> 1, wn = w & 1;
    const int quad = lane >> 4;
    const int l16 = lane & 15;

    const int r0 = tid >> 2, c0 = (tid & 3) * 8;
    const short* pA[2][2]; const short* pB[2][2];
    short* lA[2][2]; short* lB[2][2];
#pragma unroll
    for (int it = 0; it < 2; ++it)
#pragma unroll
        for (int hh = 0; hh < 2; ++hh) {
            pA[it][hh] = A + (size_t)(m0 + it * 64 + r0) * CC + hh * 32 + c0;
            pB[it][hh] = Bt + (size_t)(n0 + it * 64 + r0) * CC + hh * 32 + c0;
            lA[it][hh] = &Sbuf[hh][(it * 256 + w * 64) * 8];
            lB[it][hh] = &Sbuf[2 + hh][(it * 256 + w * 64) * 8];
        }

    floatx4 acc[4][4] = {};
    for (int kb = 0; kb < CC; kb += 64) {
        __syncthreads();
#pragma unroll
        for (int it = 0; it < 2; ++it)
#pragma unroll
            for (int hh = 0; hh < 2; ++hh) {
                gload_lds16(pA[it][hh] + kb, lA[it][hh]);
                gload_lds16(pB[it][hh] + kb, lB[it][hh]);
            }
        __syncthreads();
#pragma unroll
        for (int kk = 0; kk < 2; ++kk) {
            short8 af[4], bf[4];
#pragma unroll
            for (int mi = 0; mi < 4; ++mi)
                af[mi] = *(const short8*)&Sbuf[kk][(wm * 64 + mi * 16 + l16) * 32 + quad * 8];
#pragma unroll
            for (int ni = 0; ni < 4; ++ni)
                bf[ni] = *(const short8*)&Sbuf[2 + kk][(wn * 64 + ni * 16 + l16) * 32 + quad * 8];
#pragma unroll
            for (int mi = 0; mi < 4; ++mi)
#pragma unroll
                for (int ni = 0; ni < 4; ++ni)
                    acc[mi][ni] = __builtin_amdgcn_mfma_f32_16x16x32_bf16(af[mi], bf[ni], acc[mi][ni], 0, 0, 0);
        }
    }

    // ---- epilogue: acc -> LDS tile (swizzled) -> coalesced 16B stores ----
    __syncthreads();                    // staging LDS dead; safe to reuse
    char* T = (char*)&Sbuf[0][0];
    const int which = n0 >> 10;         // block-uniform: 0=Q, 1=K, 2=V

    if (which < 2) {
        const float sc = (which == 0) ? QSCALE : 1.0f;
#pragma unroll
        for (int mi = 0; mi < 4; ++mi)
#pragma unroll
            for (int ni = 0; ni < 4; ++ni) {
                int nl = wn * 64 + ni * 16 + l16;
                float bv = bias[n0 + nl];
#pragma unroll
                for (int r = 0; r < 4; ++r) {
                    int ml = wm * 64 + mi * 16 + quad * 4 + r;
                    *(short*)(T + ml * 256 + ((nl * 2) ^ ((ml & 7) << 4))) =
                        f2bf((acc[mi][ni][r] + bv) * sc);
                }
            }
        __syncthreads();
        short* base = (which == 0) ? Q : Kb;
        const int row = tid >> 4, seg = tid & 15;
#pragma unroll
        for (int p = 0; p < 8; ++p) {
            int m = p * 16 + row;
            uint4v v = *(uint4v*)(T + m * 256 + ((seg * 16) ^ ((m & 7) << 4)));
            int gn = n0 + seg * 8 - which * 1024;          // 0..1023
            int hh2 = gn >> 6, d = gn & 63;
            *(uint4v*)&base[((size_t)hh2 * TT + (m0 + m)) * DH + d] = v;
        }
    } else {
#pragma unroll
        for (int mi = 0; mi < 4; ++mi)
#pragma unroll
            for (int ni = 0; ni < 4; ++ni) {
                int nl = wn * 64 + ni * 16 + l16;
                float bv = bias[n0 + nl];
                int ml0 = wm * 64 + mi * 16 + quad * 4;
                uint2 pk;
                pk.x = pk_rne(acc[mi][ni][0] + bv, acc[mi][ni][1] + bv);
                pk.y = pk_rne(acc[mi][ni][2] + bv, acc[mi][ni][3] + bv);
                *(uint2*)(T + nl * 256 + ((ml0 * 2) ^ ((nl & 7) << 4))) = pk;
            }
        __syncthreads();
        const int row = tid >> 4, seg = tid & 15;
#pragma unroll
        for (int p = 0; p < 8; ++p) {
            int n = p * 16 + row;
            uint4v v = *(uint4v*)(T + n * 256 + ((seg * 16) ^ ((n & 7) << 4)));
            int gn = n0 + n - 2048;                        // 0..1023
            int hh2 = gn >> 6, d = gn & 63;
            *(uint4v*)&Vtg[((size_t)hh2 * DH + d) * TT + m0 + seg * 8] = v;
        }
    }
}

// ---------------- flash attention v17: v15 + triple-buffer counted vmcnt (T4) -----
// v15 (75.0us): per-tile s_waitcnt vmcnt(0) waits on the JUST-ISSUED next-tile
// stage — exposed whenever compute doesn't fully cover the K/V gather latency,
// especially in the solo-heavy phase (occupancy 12.9% => ~half the dispatch has
// no partner block to hide it). T4 fix: stage TWO tiles ahead into a third
// buffer; end-of-iter waits vmcnt(4) — the 4 newest (t+2) loads stay in flight
// across the barrier, the 4 older (t+1) loads are guaranteed landed (each wave
// issues exactly 4 loads per stage; vmcnt drains oldest-first). Last two
// iterations fall back to vmcnt(0) (block-uniform tail). LDS 48KB x 2 blocks =
// 96KB <= 160KB, residency unchanged. Compute body byte-identical to v15.
// Failure rule: k_attn >= 75.5us -> revert to R13, close at 206.3.
__device__ __forceinline__ void stage_kv(const short* __restrict__ Kp,
                                         const short* __restrict__ Vp,
                                         short* lk, short* lv,
                                         int k0, int w, int lane) {
    const int p = lane & 7;
    const int rl = lane >> 3;                  // 0..7
#pragma unroll
    for (int i = 0; i < 2; ++i) {
        const int R = w * 16 + i * 8 + rl;     // row staged by this lane
        const int u = p ^ (R & 7);             // logical 16B unit for phys slot p
        gload_lds16(Kp + (size_t)(k0 + R) * DH + u * 8, lk + (w * 16 + i * 8) * 64);
        gload_lds16(Vp + (size_t)R * TT + k0 + u * 8,   lv + (w * 16 + i * 8) * 64);
    }
}

__global__ __launch_bounds__(256) void k_attn(const short* __restrict__ Qh,
                                              const short* __restrict__ Kh,
                                              const short* __restrict__ VhT,
                                              short* __restrict__ Ob) {
    const int h = blockIdx.x;
    const int y = blockIdx.y;                  // 0..31
    const int qi = (y < 16) ? (31 - y) : (y - 16);   // heavy first
    const int tid = threadIdx.x;
    const int w = tid >> 6;
    const int lane = tid & 63;
    const int l31 = lane & 31;
    const int hi = lane >> 5;

    __shared__ __attribute__((aligned(16))) short ldsK[3][4096];
    __shared__ __attribute__((aligned(16))) short ldsV[3][4096];

    const short* Qp = Qh + (size_t)h * TT * DH;
    const short* Kp = Kh + (size_t)h * TT * DH;
    const short* Vp = VhT + (size_t)h * DH * TT;

    const int qs = qi * 128 + w * 32;          // this warp's first q row
    const int nk = 2 * qi + 2;                 // 64-wide k-tiles (nk >= 2 always)

    // Q B-frags (persistent): B[d][q=l31], 8 consecutive d per lane
    short8 bq[4];
#pragma unroll
    for (int st = 0; st < 4; ++st)
        bq[st] = *(const short8*)&Qp[(size_t)(qs + l31) * DH + st * 16 + hi * 8];

    floatx16 accO0 = {}, accO1 = {};
    float l_acc = 0.f;

    // prologue: stage tiles 0 and 1 (nk >= 2); wait only for tile 0 (vmcnt(4))
    stage_kv(Kp, Vp, &ldsK[0][0], &ldsV[0][0], 0, w, lane);
    stage_kv(Kp, Vp, &ldsK[1][0], &ldsV[1][0], 64, w, lane);
    asm volatile("s_waitcnt vmcnt(4)" ::: "memory");
    __builtin_amdgcn_s_barrier();
    asm volatile("" ::: "memory");

    int cb = 0;                                // compute buffer = t % 3
    int sb = 2;                                // stage buffer  = (t+2) % 3
    for (int t = 0; t < nk; ++t) {
        const int k0 = t * 64;
        const bool deep = (t + 2 < nk);
        // stage tile t+2 two-deep (async; stays in flight across the barrier)
        if (deep)
            stage_kv(Kp, Vp, &ldsK[sb][0], &ldsV[sb][0], k0 + 128, w, lane);

        const bool skip = (k0 > qs + 31);      // tile fully above causal diagonal
        if (!skip) {
            const short* lk = &ldsK[cb][0];
            const short* lv = &ldsV[cb][0];
            const bool masked = (k0 + 63 > qs);
            const int qg = qs + l31;

            // K A-frags from LDS (swizzled read)
            short8 ak[2][4];
#pragma unroll
            for (int sub = 0; sub < 2; ++sub)
#pragma unroll
                for (int st = 0; st < 4; ++st)
                    ak[sub][st] = *(const short8*)&lk[(sub * 32 + l31) * 64 +
                                                     (((st * 2 + hi) ^ (l31 & 7)) * 8)];

            // S^T[64k][32q] in two 32-k halves
            floatx16 s0 = {}, s1 = {};
#pragma unroll
            for (int st = 0; st < 4; ++st) {
                s0 = __builtin_amdgcn_mfma_f32_32x32x16_bf16(ak[0][st], bq[st], s0, 0, 0, 0);
                s1 = __builtin_amdgcn_mfma_f32_32x32x16_bf16(ak[1][st], bq[st], s1, 0, 0, 0);
            }

#pragma unroll
            for (int sub = 0; sub < 2; ++sub) {
                float p[16];
#pragma unroll
                for (int r = 0; r < 16; ++r)
                    p[r] = __builtin_amdgcn_exp2f(sub == 0 ? s0[r] : s1[r]);
                if (masked) {
#pragma unroll
                    for (int r = 0; r < 16; ++r) {
                        int kg = k0 + sub * 32 + (r & 3) + 8 * (r >> 2) + 4 * hi;
                        p[r] = (kg <= qg) ? p[r] : 0.f;
                    }
                }
                {   // shallow tree-sum into l
                    float t0 = (p[0] + p[1]) + (p[2] + p[3]);
                    float t1 = (p[4] + p[5]) + (p[6] + p[7]);
                    float t2 = (p[8] + p[9]) + (p[10] + p[11]);
                    float t3 = (p[12] + p[13]) + (p[14] + p[15]);
                    l_acc += (t0 + t1) + (t2 + t3);
                }
                // T12 relayout: D-layout -> PV A-operand (P[q=l31][k 8-consec])
                unsigned pa[8];
                pa[0] = pk_trunc(p[0], p[1]);   pa[1] = pk_trunc(p[2], p[3]);
                pa[2] = pk_trunc(p[4], p[5]);   pa[3] = pk_trunc(p[6], p[7]);
                pa[4] = pk_trunc(p[8], p[9]);   pa[5] = pk_trunc(p[10], p[11]);
                pa[6] = pk_trunc(p[12], p[13]); pa[7] = pk_trunc(p[14], p[15]);
                asm("v_permlane32_swap_b32 %0, %1" : "+v"(pa[0]), "+v"(pa[2]));
                asm("v_permlane32_swap_b32 %0, %1" : "+v"(pa[1]), "+v"(pa[3]));
                asm("v_permlane32_swap_b32 %0, %1" : "+v"(pa[4]), "+v"(pa[6]));
                asm("v_permlane32_swap_b32 %0, %1" : "+v"(pa[5]), "+v"(pa[7]));
                uint4v a0v = {pa[0], pa[1], pa[2], pa[3]};   // k sub*32+0..15
                uint4v a1v = {pa[4], pa[5], pa[6], pa[7]};   // k sub*32+16..31
                short8 A0 = __builtin_bit_cast(short8, a0v);
                short8 A1 = __builtin_bit_cast(short8, a1v);

                // V B-frags from LDS (swizzled read); rows d = db*32+l31
                short8 vf00 = *(const short8*)&lv[(l31) * 64 +
                                                  (((sub * 4 + hi) ^ (l31 & 7)) * 8)];
                short8 vf01 = *(const short8*)&lv[(l31) * 64 +
                                                  (((sub * 4 + 2 + hi) ^ (l31 & 7)) * 8)];
                short8 vf10 = *(const short8*)&lv[(32 + l31) * 64 +
                                                  (((sub * 4 + hi) ^ (l31 & 7)) * 8)];
                short8 vf11 = *(const short8*)&lv[(32 + l31) * 64 +
                                                  (((sub * 4 + 2 + hi) ^ (l31 & 7)) * 8)];

                accO0 = __builtin_amdgcn_mfma_f32_32x32x16_bf16(A0, vf00, accO0, 0, 0, 0);
                accO0 = __builtin_amdgcn_mfma_f32_32x32x16_bf16(A1, vf01, accO0, 0, 0, 0);
                accO1 = __builtin_amdgcn_mfma_f32_32x32x16_bf16(A0, vf10, accO1, 0, 0, 0);
                accO1 = __builtin_amdgcn_mfma_f32_32x32x16_bf16(A1, vf11, accO1, 0, 0, 0);
            }
        }

        // counted wait: tile t+1's 4 loads are the OLDEST outstanding; leaving
        // <=4 (tile t+2's) in flight guarantees t+1 landed. Tail (last 2 iters):
        // nothing newer in flight -> full drain. Block-uniform condition.
        if (deep)
            asm volatile("s_waitcnt vmcnt(4)" ::: "memory");
        else
            asm volatile("s_waitcnt vmcnt(0)" ::: "memory");
        __builtin_amdgcn_s_barrier();
        asm volatile("" ::: "memory");
        cb = (cb == 2) ? 0 : cb + 1;
        sb = (sb == 2) ? 0 : sb + 1;
    }

    // l: halves (hi=0/1) hold complementary k-rows for q=l31
    l_acc += __shfl_xor(l_acc, 32, 64);
    float inv = __builtin_amdgcn_rcpf(l_acc);

    // epilogue: accO row q = (r&3)+8(r>>2)+4hi, col d = l31 (+32 for accO1)
#pragma unroll
    for (int r = 0; r < 16; ++r) {
        int qr = (r & 3) + 8 * (r >> 2) + 4 * hi;   // < 32
        float iv = __shfl(inv, qr, 64);
        int qg = qs + qr;
        Ob[(size_t)qg * CC + h * DH + l31]      = f2bf(accO0[r] * iv);
        Ob[(size_t)qg * CC + h * DH + 32 + l31] = f2bf(accO1[r] * iv);
    }
}

// ---------------- GEMM2 v2: out = Ob @ w_proj + b, 64x128 tiles -------------------
// 512 blocks = 2/CU (R9: -4us vs 1 blk/CU).
__global__ __launch_bounds__(256) void k_gemm_proj(const short* __restrict__ A,
                                                   const short* __restrict__ Bt,
                                                   const float* __restrict__ bias,
                                                   float* __restrict__ out) {
    const int m0 = blockIdx.y * 64;
    const int n0 = blockIdx.x * 128;
    __shared__ __attribute__((aligned(16))) short As[2][64 * 32];
    __shared__ __attribute__((aligned(16))) short Bs[2][128 * 32];
    const int tid = threadIdx.x;
    const int lane = tid & 63;
    const int w = tid >> 6;
    const int quad = lane >> 4;
    const int l16 = lane & 15;

    const int r0 = tid >> 2, c0 = (tid & 3) * 8;
    const short* pA[2]; const short* pB[2][2];
    short* lA[2]; short* lB[2][2];
#pragma unroll
    for (int hh = 0; hh < 2; ++hh) {
        pA[hh] = A + (size_t)(m0 + r0) * CC + hh * 32 + c0;
        lA[hh] = &As[hh][w * 512];
#pragma unroll
        for (int it = 0; it < 2; ++it) {
            pB[it][hh] = Bt + (size_t)(n0 + it * 64 + r0) * CC + hh * 32 + c0;
            lB[it][hh] = &Bs[hh][(it * 256 + w * 64) * 8];
        }
    }

    floatx4 acc[4][2] = {};
    for (int kb = 0; kb < CC; kb += 64) {
        __syncthreads();
#pragma unroll
        for (int hh = 0; hh < 2; ++hh) {
            gload_lds16(pA[hh] + kb, lA[hh]);
#pragma unroll
            for (int it = 0; it < 2; ++it)
                gload_lds16(pB[it][hh] + kb, lB[it][hh]);
        }
        __syncthreads();
#pragma unroll
        for (int kk = 0; kk < 2; ++kk) {
            short8 af[4], bf[2];
#pragma unroll
            for (int mi = 0; mi < 4; ++mi)
                af[mi] = *(const short8*)&As[kk][(mi * 16 + l16) * 32 + quad * 8];
#pragma unroll
            for (int ni = 0; ni < 2; ++ni)
                bf[ni] = *(const short8*)&Bs[kk][(w * 32 + ni * 16 + l16) * 32 + quad * 8];
#pragma unroll
            for (int mi = 0; mi < 4; ++mi)
#pragma unroll
                for (int ni = 0; ni < 2; ++ni)
                    acc[mi][ni] = __builtin_amdgcn_mfma_f32_16x16x32_bf16(af[mi], bf[ni], acc[mi][ni], 0, 0, 0);
        }
    }
#pragma unroll
    for (int mi = 0; mi < 4; ++mi) {
#pragma unroll
        for (int ni = 0; ni < 2; ++ni) {
            int gm = m0 + mi * 16 + quad * 4;
            int gn = n0 + w * 32 + ni * 16 + l16;
            float bv = bias[gn];
#pragma unroll
            for (int r = 0; r < 4; ++r)
                out[(size_t)(gm + r) * CC + gn] = acc[mi][ni][r] + bv;
        }
    }
}

extern "C" void kernel_launch(void* const* d_in, const int* in_sizes, int n_in,
                              void* d_out, int out_size, void* d_ws, size_t ws_size,
                              hipStream_t stream) {
    const float* x      = (const float*)d_in[0];
    const float* w_qkv  = (const float*)d_in[1];
    const float* b_qkv  = (const float*)d_in[2];
    const float* w_proj = (const float*)d_in[3];
    const float* b_proj = (const float*)d_in[4];
    float* out = (float*)d_out;
    char* ws = (char*)d_ws;

    short* xb     = (short*)(ws);                       // 8388608 B
    short* wqkvT  = (short*)(ws + 8388608);             // 6291456 B
    short* wprojT = (short*)(ws + 14680064);            // 2097152 B
    short* Qh     = (short*)(ws + 16777216);            // 8388608 B
    short* Kh     = (short*)(ws + 25165824);
    short* VhT    = (short*)(ws + 33554432);            // [H,64,T]
    short* Ob     = (short*)(ws + 41943040);
    // total 50331648 B (48 MB)

    k_prep<<<8192, 256, 0, stream>>>(x, xb, w_qkv, wqkvT, w_proj, wprojT);
    k_gemm_qkv<<<dim3(N3C / 128, TT / 128), 256, 0, stream>>>(xb, wqkvT, b_qkv, Qh, Kh, VhT);
    k_attn<<<dim3(NHEAD, 32), 256, 0, stream>>>(Qh, Kh, VhT, Ob);
    k_gemm_proj<<<dim3(CC / 128, TT / 64), 256, 0, stream>>>(Ob, wprojT, b_proj, out);
}

// Round 18
// 205.451 us; speedup vs baseline: 1.0175x; 1.0175x over previous
//
#include <hip/hip_runtime.h>
#include <hip/hip_bf16.h>

#define TT 4096
#define CC 1024
#define NHEAD 16
#define DH 64
#define N3C 3072

typedef __attribute__((ext_vector_type(8))) short short8;
typedef __attribute__((ext_vector_type(4))) float floatx4;
typedef __attribute__((ext_vector_type(16))) float floatx16;
typedef __attribute__((ext_vector_type(4))) unsigned int uint4v;

// Q pre-scale: 1/sqrt(64) * log2(e)  (softmax in exp2 domain, m=0 fixed)
#define QSCALE 0.18033688011112042f

__device__ __forceinline__ short f2bf(float f) {
    union { __hip_bfloat16 h; short s; } u;
    u.h = __float2bfloat16(f);
    return u.s;
}

// async global->LDS 16B per lane; LDS dest = wave-uniform base + lane*16
__device__ __forceinline__ void gload_lds16(const void* g, void* l) {
    __builtin_amdgcn_global_load_lds(
        (const __attribute__((address_space(1))) unsigned int*)(unsigned long long)g,
        (__attribute__((address_space(3))) unsigned int*)(unsigned int)(unsigned long long)l,
        16, 0, 0);
}

// pack two fp32 -> bf16x2 by truncation (1 v_perm) — used only for attn P
__device__ __forceinline__ unsigned pk_trunc(float lo, float hi) {
    return __builtin_amdgcn_perm(__float_as_uint(hi), __float_as_uint(lo), 0x07060302u);
}

// pack two fp32 -> bf16x2 with RNE rounding (numerics identical to f2bf path)
__device__ __forceinline__ unsigned pk_rne(float lo, float hi) {
    unsigned a = (unsigned short)f2bf(lo);
    unsigned b = (unsigned short)f2bf(hi);
    return a | (b << 16);
}

// ---------------- fused prep: cvt x->bf16, transpose both weights ----------------
__device__ __forceinline__ void tr_body(const float* __restrict__ in, short* __restrict__ out,
                                        int K, int N, int bx, int by, int tid, float (*tile)[33]) {
    int nt = bx * 32, kt = by * 32;
    int tx = tid & 31, ty = tid >> 5;
#pragma unroll
    for (int i = 0; i < 32; i += 8)
        tile[ty + i][tx] = in[(size_t)(kt + ty + i) * N + nt + tx];
    __syncthreads();
#pragma unroll
    for (int i = 0; i < 32; i += 8)
        out[(size_t)(nt + ty + i) * K + kt + tx] = f2bf(tile[tx][ty + i]);
}

__global__ void k_prep(const float* __restrict__ x, short* __restrict__ xb,
                       const float* __restrict__ w_qkv, short* __restrict__ wqkvT,
                       const float* __restrict__ w_proj, short* __restrict__ wprojT) {
    __shared__ float tile[32][33];
    int id = blockIdx.x;
    int tid = threadIdx.x;
    if (id < 4096) {
        int i = (id * 256 + tid) * 4;
        float4 v = *(const float4*)&x[i];
        short4 r;
        r.x = f2bf(v.x); r.y = f2bf(v.y); r.z = f2bf(v.z); r.w = f2bf(v.w);
        *(short4*)&xb[i] = r;
    } else if (id < 4096 + 3072) {
        int r = id - 4096;
        tr_body(w_qkv, wqkvT, CC, N3C, r % 96, r / 96, tid, tile);
    } else {
        int r = id - 7168;
        tr_body(w_proj, wprojT, CC, CC, r & 31, r >> 5, tid, tile);
    }
}

// ---------------- GEMM1 v2: qkv = x @ w_qkv + b, LDS re-layout epilogue -----------
__global__ __launch_bounds__(256) void k_gemm_qkv(const short* __restrict__ A,
                                                  const short* __restrict__ Bt,
                                                  const float* __restrict__ bias,
                                                  short* __restrict__ Q,
                                                  short* __restrict__ Kb,
                                                  short* __restrict__ Vtg) {
    const int m0 = blockIdx.y * 128;
    const int n0 = blockIdx.x * 128;
    __shared__ __attribute__((aligned(16))) short Sbuf[4][128 * 32];  // As=0/1, Bs=2/3
    const int tid = threadIdx.x;
    const int lane = tid & 63;
    const int w = tid >> 6;
    const int wm = w >> 1, wn = w & 1;
    const int quad = lane >> 4;
    const int l16 = lane & 15;

    const int r0 = tid >> 2, c0 = (tid & 3) * 8;
    const short* pA[2][2]; const short* pB[2][2];
    short* lA[2][2]; short* lB[2][2];
#pragma unroll
    for (int it = 0; it < 2; ++it)
#pragma unroll
        for (int hh = 0; hh < 2; ++hh) {
            pA[it][hh] = A + (size_t)(m0 + it * 64 + r0) * CC + hh * 32 + c0;
            pB[it][hh] = Bt + (size_t)(n0 + it * 64 + r0) * CC + hh * 32 + c0;
            lA[it][hh] = &Sbuf[hh][(it * 256 + w * 64) * 8];
            lB[it][hh] = &Sbuf[2 + hh][(it * 256 + w * 64) * 8];
        }

    floatx4 acc[4][4] = {};
    for (int kb = 0; kb < CC; kb += 64) {
        __syncthreads();
#pragma unroll
        for (int it = 0; it < 2; ++it)
#pragma unroll
            for (int hh = 0; hh < 2; ++hh) {
                gload_lds16(pA[it][hh] + kb, lA[it][hh]);
                gload_lds16(pB[it][hh] + kb, lB[it][hh]);
            }
        __syncthreads();
#pragma unroll
        for (int kk = 0; kk < 2; ++kk) {
            short8 af[4], bf[4];
#pragma unroll
            for (int mi = 0; mi < 4; ++mi)
                af[mi] = *(const short8*)&Sbuf[kk][(wm * 64 + mi * 16 + l16) * 32 + quad * 8];
#pragma unroll
            for (int ni = 0; ni < 4; ++ni)
                bf[ni] = *(const short8*)&Sbuf[2 + kk][(wn * 64 + ni * 16 + l16) * 32 + quad * 8];
#pragma unroll
            for (int mi = 0; mi < 4; ++mi)
#pragma unroll
                for (int ni = 0; ni < 4; ++ni)
                    acc[mi][ni] = __builtin_amdgcn_mfma_f32_16x16x32_bf16(af[mi], bf[ni], acc[mi][ni], 0, 0, 0);
        }
    }

    // ---- epilogue: acc -> LDS tile (swizzled) -> coalesced 16B stores ----
    __syncthreads();                    // staging LDS dead; safe to reuse
    char* T = (char*)&Sbuf[0][0];
    const int which = n0 >> 10;         // block-uniform: 0=Q, 1=K, 2=V

    if (which < 2) {
        const float sc = (which == 0) ? QSCALE : 1.0f;
#pragma unroll
        for (int mi = 0; mi < 4; ++mi)
#pragma unroll
            for (int ni = 0; ni < 4; ++ni) {
                int nl = wn * 64 + ni * 16 + l16;
                float bv = bias[n0 + nl];
#pragma unroll
                for (int r = 0; r < 4; ++r) {
                    int ml = wm * 64 + mi * 16 + quad * 4 + r;
                    *(short*)(T + ml * 256 + ((nl * 2) ^ ((ml & 7) << 4))) =
                        f2bf((acc[mi][ni][r] + bv) * sc);
                }
            }
        __syncthreads();
        short* base = (which == 0) ? Q : Kb;
        const int row = tid >> 4, seg = tid & 15;
#pragma unroll
        for (int p = 0; p < 8; ++p) {
            int m = p * 16 + row;
            uint4v v = *(uint4v*)(T + m * 256 + ((seg * 16) ^ ((m & 7) << 4)));
            int gn = n0 + seg * 8 - which * 1024;          // 0..1023
            int hh2 = gn >> 6, d = gn & 63;
            *(uint4v*)&base[((size_t)hh2 * TT + (m0 + m)) * DH + d] = v;
        }
    } else {
#pragma unroll
        for (int mi = 0; mi < 4; ++mi)
#pragma unroll
            for (int ni = 0; ni < 4; ++ni) {
                int nl = wn * 64 + ni * 16 + l16;
                float bv = bias[n0 + nl];
                int ml0 = wm * 64 + mi * 16 + quad * 4;
                uint2 pk;
                pk.x = pk_rne(acc[mi][ni][0] + bv, acc[mi][ni][1] + bv);
                pk.y = pk_rne(acc[mi][ni][2] + bv, acc[mi][ni][3] + bv);
                *(uint2*)(T + nl * 256 + ((ml0 * 2) ^ ((nl & 7) << 4))) = pk;
            }
        __syncthreads();
        const int row = tid >> 4, seg = tid & 15;
#pragma unroll
        for (int p = 0; p < 8; ++p) {
            int n = p * 16 + row;
            uint4v v = *(uint4v*)(T + n * 256 + ((seg * 16) ^ ((n & 7) << 4)));
            int gn = n0 + n - 2048;                        // 0..1023
            int hh2 = gn >> 6, d = gn & 63;
            *(uint4v*)&Vtg[((size_t)hh2 * DH + d) * TT + m0 + seg * 8] = v;
        }
    }
}

// ---------------- flash attention v15 (FINAL): LDS-staged K/V + in-reg P, 2 blk/CU
// Session-best attn: 75.0-75.2us (beats the R3-family 77.5us plateau; confirmed
// twice, R13/R15). Body: K/V staged via global_load_lds one tile ahead
// (pre-swizzled global source, linear LDS dest, swizzled reads — rule #21),
// P fully in registers via swapped QK^T (mfma_32x32x16, q=lane&31, k-rows
// (r&3)+8(r>>2)+4hi) + pk_trunc/permlane32_swap relayout. Grid (16,32) = 512
// blocks = 2 blocks/CU (R13 fix of R11's 1 blk/CU exposure, 86->75us).
// R14 (4x 2-warp blocks, 80.4us) and R16 (triple-buffer counted vmcnt, 77.8us
// steady + 30ms outlier) both violated failure rules -> reverted. This
// 4-warp/2-block double-buffer config is the measured optimum of the family.
// Balance: y<16 -> qi=31-y (heavy), y>=16 -> qi=y-16; CU c gets {c, c+256} ->
// 68 tiles for every CU. bid%8 = h%8 (R1: per-XCD L2 head affinity, ~15%).
// (R17 bench failure was container-acquire infra, same as R4; resubmitted.)
__device__ __forceinline__ void stage_kv(const short* __restrict__ Kp,
                                         const short* __restrict__ Vp,
                                         short* lk, short* lv,
                                         int k0, int w, int lane) {
    const int p = lane & 7;
    const int rl = lane >> 3;                  // 0..7
#pragma unroll
    for (int i = 0; i < 2; ++i) {
        const int R = w * 16 + i * 8 + rl;     // row staged by this lane
        const int u = p ^ (R & 7);             // logical 16B unit for phys slot p
        gload_lds16(Kp + (size_t)(k0 + R) * DH + u * 8, lk + (w * 16 + i * 8) * 64);
        gload_lds16(Vp + (size_t)R * TT + k0 + u * 8,   lv + (w * 16 + i * 8) * 64);
    }
}

__global__ __launch_bounds__(256) void k_attn(const short* __restrict__ Qh,
                                              const short* __restrict__ Kh,
                                              const short* __restrict__ VhT,
                                              short* __restrict__ Ob) {
    const int h = blockIdx.x;
    const int y = blockIdx.y;                  // 0..31
    const int qi = (y < 16) ? (31 - y) : (y - 16);   // heavy first
    const int tid = threadIdx.x;
    const int w = tid >> 6;
    const int lane = tid & 63;
    const int l31 = lane & 31;
    const int hi = lane >> 5;

    __shared__ __attribute__((aligned(16))) short ldsK[2][4096];
    __shared__ __attribute__((aligned(16))) short ldsV[2][4096];

    const short* Qp = Qh + (size_t)h * TT * DH;
    const short* Kp = Kh + (size_t)h * TT * DH;
    const short* Vp = VhT + (size_t)h * DH * TT;

    const int qs = qi * 128 + w * 32;          // this warp's first q row
    const int nk = 2 * qi + 2;                 // 64-wide k-tiles for the block

    // Q B-frags (persistent): B[d][q=l31], 8 consecutive d per lane
    short8 bq[4];
#pragma unroll
    for (int st = 0; st < 4; ++st)
        bq[st] = *(const short8*)&Qp[(size_t)(qs + l31) * DH + st * 16 + hi * 8];

    floatx16 accO0 = {}, accO1 = {};
    float l_acc = 0.f;

    // stage tile 0 into buf 0
    stage_kv(Kp, Vp, &ldsK[0][0], &ldsV[0][0], 0, w, lane);
    asm volatile("s_waitcnt vmcnt(0)" ::: "memory");
    __builtin_amdgcn_s_barrier();
    asm volatile("" ::: "memory");

    int buf = 0;
    for (int t = 0; t < nk; ++t) {
        const int k0 = t * 64;
        // stage next tile into the other buffer (async; drained before barrier)
        if (t + 1 < nk)
            stage_kv(Kp, Vp, &ldsK[buf ^ 1][0], &ldsV[buf ^ 1][0], k0 + 64, w, lane);

        const bool skip = (k0 > qs + 31);      // tile fully above causal diagonal
        if (!skip) {
            const short* lk = &ldsK[buf][0];
            const short* lv = &ldsV[buf][0];
            const bool masked = (k0 + 63 > qs);
            const int qg = qs + l31;

            // K A-frags from LDS (swizzled read)
            short8 ak[2][4];
#pragma unroll
            for (int sub = 0; sub < 2; ++sub)
#pragma unroll
                for (int st = 0; st < 4; ++st)
                    ak[sub][st] = *(const short8*)&lk[(sub * 32 + l31) * 64 +
                                                     (((st * 2 + hi) ^ (l31 & 7)) * 8)];

            // S^T[64k][32q] in two 32-k halves
            floatx16 s0 = {}, s1 = {};
#pragma unroll
            for (int st = 0; st < 4; ++st) {
                s0 = __builtin_amdgcn_mfma_f32_32x32x16_bf16(ak[0][st], bq[st], s0, 0, 0, 0);
                s1 = __builtin_amdgcn_mfma_f32_32x32x16_bf16(ak[1][st], bq[st], s1, 0, 0, 0);
            }

#pragma unroll
            for (int sub = 0; sub < 2; ++sub) {
                float p[16];
#pragma unroll
                for (int r = 0; r < 16; ++r)
                    p[r] = __builtin_amdgcn_exp2f(sub == 0 ? s0[r] : s1[r]);
                if (masked) {
#pragma unroll
                    for (int r = 0; r < 16; ++r) {
                        int kg = k0 + sub * 32 + (r & 3) + 8 * (r >> 2) + 4 * hi;
                        p[r] = (kg <= qg) ? p[r] : 0.f;
                    }
                }
                {   // shallow tree-sum into l
                    float t0 = (p[0] + p[1]) + (p[2] + p[3]);
                    float t1 = (p[4] + p[5]) + (p[6] + p[7]);
                    float t2 = (p[8] + p[9]) + (p[10] + p[11]);
                    float t3 = (p[12] + p[13]) + (p[14] + p[15]);
                    l_acc += (t0 + t1) + (t2 + t3);
                }
                // T12 relayout: D-layout -> PV A-operand (P[q=l31][k 8-consec])
                unsigned pa[8];
                pa[0] = pk_trunc(p[0], p[1]);   pa[1] = pk_trunc(p[2], p[3]);
                pa[2] = pk_trunc(p[4], p[5]);   pa[3] = pk_trunc(p[6], p[7]);
                pa[4] = pk_trunc(p[8], p[9]);   pa[5] = pk_trunc(p[10], p[11]);
                pa[6] = pk_trunc(p[12], p[13]); pa[7] = pk_trunc(p[14], p[15]);
                asm("v_permlane32_swap_b32 %0, %1" : "+v"(pa[0]), "+v"(pa[2]));
                asm("v_permlane32_swap_b32 %0, %1" : "+v"(pa[1]), "+v"(pa[3]));
                asm("v_permlane32_swap_b32 %0, %1" : "+v"(pa[4]), "+v"(pa[6]));
                asm("v_permlane32_swap_b32 %0, %1" : "+v"(pa[5]), "+v"(pa[7]));
                uint4v a0v = {pa[0], pa[1], pa[2], pa[3]};   // k sub*32+0..15
                uint4v a1v = {pa[4], pa[5], pa[6], pa[7]};   // k sub*32+16..31
                short8 A0 = __builtin_bit_cast(short8, a0v);
                short8 A1 = __builtin_bit_cast(short8, a1v);

                // V B-frags from LDS (swizzled read); rows d = db*32+l31
                short8 vf00 = *(const short8*)&lv[(l31) * 64 +
                                                  (((sub * 4 + hi) ^ (l31 & 7)) * 8)];
                short8 vf01 = *(const short8*)&lv[(l31) * 64 +
                                                  (((sub * 4 + 2 + hi) ^ (l31 & 7)) * 8)];
                short8 vf10 = *(const short8*)&lv[(32 + l31) * 64 +
                                                  (((sub * 4 + hi) ^ (l31 & 7)) * 8)];
                short8 vf11 = *(const short8*)&lv[(32 + l31) * 64 +
                                                  (((sub * 4 + 2 + hi) ^ (l31 & 7)) * 8)];

                accO0 = __builtin_amdgcn_mfma_f32_32x32x16_bf16(A0, vf00, accO0, 0, 0, 0);
                accO0 = __builtin_amdgcn_mfma_f32_32x32x16_bf16(A1, vf01, accO0, 0, 0, 0);
                accO1 = __builtin_amdgcn_mfma_f32_32x32x16_bf16(A0, vf10, accO1, 0, 0, 0);
                accO1 = __builtin_amdgcn_mfma_f32_32x32x16_bf16(A1, vf11, accO1, 0, 0, 0);
            }
        }

        // own stage loads landed (issued ~600cy ago); barrier publishes both bufs
        asm volatile("s_waitcnt vmcnt(0)" ::: "memory");
        __builtin_amdgcn_s_barrier();
        asm volatile("" ::: "memory");
        buf ^= 1;
    }

    // l: halves (hi=0/1) hold complementary k-rows for q=l31
    l_acc += __shfl_xor(l_acc, 32, 64);
    float inv = __builtin_amdgcn_rcpf(l_acc);

    // epilogue: accO row q = (r&3)+8(r>>2)+4hi, col d = l31 (+32 for accO1)
#pragma unroll
    for (int r = 0; r < 16; ++r) {
        int qr = (r & 3) + 8 * (r >> 2) + 4 * hi;   // < 32
        float iv = __shfl(inv, qr, 64);
        int qg = qs + qr;
        Ob[(size_t)qg * CC + h * DH + l31]      = f2bf(accO0[r] * iv);
        Ob[(size_t)qg * CC + h * DH + 32 + l31] = f2bf(accO1[r] * iv);
    }
}

// ---------------- GEMM2 v2: out = Ob @ w_proj + b, 64x128 tiles -------------------
// 512 blocks = 2/CU (R9: -4us vs 1 blk/CU).
__global__ __launch_bounds__(256) void k_gemm_proj(const short* __restrict__ A,
                                                   const short* __restrict__ Bt,
                                                   const float* __restrict__ bias,
                                                   float* __restrict__ out) {
    const int m0 = blockIdx.y * 64;
    const int n0 = blockIdx.x * 128;
    __shared__ __attribute__((aligned(16))) short As[2][64 * 32];
    __shared__ __attribute__((aligned(16))) short Bs[2][128 * 32];
    const int tid = threadIdx.x;
    const int lane = tid & 63;
    const int w = tid >> 6;
    const int quad = lane >> 4;
    const int l16 = lane & 15;

    const int r0 = tid >> 2, c0 = (tid & 3) * 8;
    const short* pA[2]; const short* pB[2][2];
    short* lA[2]; short* lB[2][2];
#pragma unroll
    for (int hh = 0; hh < 2; ++hh) {
        pA[hh] = A + (size_t)(m0 + r0) * CC + hh * 32 + c0;
        lA[hh] = &As[hh][w * 512];
#pragma unroll
        for (int it = 0; it < 2; ++it) {
            pB[it][hh] = Bt + (size_t)(n0 + it * 64 + r0) * CC + hh * 32 + c0;
            lB[it][hh] = &Bs[hh][(it * 256 + w * 64) * 8];
        }
    }

    floatx4 acc[4][2] = {};
    for (int kb = 0; kb < CC; kb += 64) {
        __syncthreads();
#pragma unroll
        for (int hh = 0; hh < 2; ++hh) {
            gload_lds16(pA[hh] + kb, lA[hh]);
#pragma unroll
            for (int it = 0; it < 2; ++it)
                gload_lds16(pB[it][hh] + kb, lB[it][hh]);
        }
        __syncthreads();
#pragma unroll
        for (int kk = 0; kk < 2; ++kk) {
            short8 af[4], bf[2];
#pragma unroll
            for (int mi = 0; mi < 4; ++mi)
                af[mi] = *(const short8*)&As[kk][(mi * 16 + l16) * 32 + quad * 8];
#pragma unroll
            for (int ni = 0; ni < 2; ++ni)
                bf[ni] = *(const short8*)&Bs[kk][(w * 32 + ni * 16 + l16) * 32 + quad * 8];
#pragma unroll
            for (int mi = 0; mi < 4; ++mi)
#pragma unroll
                for (int ni = 0; ni < 2; ++ni)
                    acc[mi][ni] = __builtin_amdgcn_mfma_f32_16x16x32_bf16(af[mi], bf[ni], acc[mi][ni], 0, 0, 0);
        }
    }
#pragma unroll
    for (int mi = 0; mi < 4; ++mi) {
#pragma unroll
        for (int ni = 0; ni < 2; ++ni) {
            int gm = m0 + mi * 16 + quad * 4;
            int gn = n0 + w * 32 + ni * 16 + l16;
            float bv = bias[gn];
#pragma unroll
            for (int r = 0; r < 4; ++r)
                out[(size_t)(gm + r) * CC + gn] = acc[mi][ni][r] + bv;
        }
    }
}

extern "C" void kernel_launch(void* const* d_in, const int* in_sizes, int n_in,
                              void* d_out, int out_size, void* d_ws, size_t ws_size,
                              hipStream_t stream) {
    const float* x      = (const float*)d_in[0];
    const float* w_qkv  = (const float*)d_in[1];
    const float* b_qkv  = (const float*)d_in[2];
    const float* w_proj = (const float*)d_in[3];
    const float* b_proj = (const float*)d_in[4];
    float* out = (float*)d_out;
    char* ws = (char*)d_ws;

    short* xb     = (short*)(ws);                       // 8388608 B
    short* wqkvT  = (short*)(ws + 8388608);             // 6291456 B
    short* wprojT = (short*)(ws + 14680064);            // 2097152 B
    short* Qh     = (short*)(ws + 16777216);            // 8388608 B
    short* Kh     = (short*)(ws + 25165824);
    short* VhT    = (short*)(ws + 33554432);            // [H,64,T]
    short* Ob     = (short*)(ws + 41943040);
    // total 50331648 B (48 MB)

    k_prep<<<8192, 256, 0, stream>>>(x, xb, w_qkv, wqkvT, w_proj, wprojT);
    k_gemm_qkv<<<dim3(N3C / 128, TT / 128), 256, 0, stream>>>(xb, wqkvT, b_qkv, Qh, Kh, VhT);
    k_attn<<<dim3(NHEAD, 32), 256, 0, stream>>>(Qh, Kh, VhT, Ob);
    k_gemm_proj<<<dim3(CC / 128, TT / 64), 256, 0, stream>>>(Ob, wprojT, b_proj, out);
}